// Round 7
// baseline (92.261 us; speedup 1.0000x reference)
//
#include <hip/hip_runtime.h>
#include <cstdint>

#define B_   8
#define C_   256
#define H_   64
#define W_   64
#define HW_  4096
#define NH_  8
#define NP_  4
#define DH_  32

typedef unsigned int u32;
typedef unsigned short u16;
typedef __attribute__((ext_vector_type(8))) short bf16x8;
typedef __attribute__((ext_vector_type(4))) float f32x4;
typedef __attribute__((ext_vector_type(4))) u32 u32x4;
typedef __attribute__((address_space(3))) u32 as3_u32;
typedef __attribute__((address_space(1))) u32 as1_u32;

__device__ __forceinline__ u16 f2bf(float f) {
  u32 u = __builtin_bit_cast(u32, f);
  return (u16)((u + 0x7FFFu + ((u >> 16) & 1u)) >> 16);
}
__device__ __forceinline__ float bflo(u32 v) { return __builtin_bit_cast(float, v << 16); }
__device__ __forceinline__ float bfhi(u32 v) { return __builtin_bit_cast(float, v & 0xFFFF0000u); }

// ---------------------------------------------------------------------------
// Kernel 1: merged prep (unchanged). blocks [0,4096): key transpose->bf16;
// [4096,4352): offsets MFMA GEMM + softmax -> params; [4352,4416): w_proj->bf16.
// ---------------------------------------------------------------------------
__global__ __launch_bounds__(256) void k_prep(const float* __restrict__ query,
                                              const float* __restrict__ key,
                                              const float* __restrict__ w_off,
                                              const float* __restrict__ b_off,
                                              const float* __restrict__ w_proj,
                                              float4* __restrict__ params,
                                              u32* __restrict__ key_t2,
                                              uint2* __restrict__ wproj_bf) {
  __shared__ char smem[57344];
  const int bid = blockIdx.x;
  const int t = threadIdx.x;

  if (bid < 4096) {
    float* tile = (float*)smem;  // 32 x 65
    const int g = bid >> 6;
    const int hw0 = (bid & 63) << 6;
    const float* kg = key + (size_t)g * DH_ * HW_ + hw0;
    #pragma unroll
    for (int k = 0; k < 8; ++k) {
      int idx = t + k * 256;
      int d = idx >> 6, j = idx & 63;
      tile[d * 65 + j] = kg[d * HW_ + j];
    }
    __syncthreads();
    u32* kt = key_t2 + ((size_t)g * HW_ + hw0) * 16;
    #pragma unroll
    for (int k = 0; k < 4; ++k) {
      int idx = t + k * 256;
      int j = idx >> 4, dp = idx & 15;
      u32 v = (u32)f2bf(tile[(2 * dp) * 65 + j]) | ((u32)f2bf(tile[(2 * dp + 1) * 65 + j]) << 16);
      kt[j * 16 + dp] = v;
    }
  } else if (bid < 4352) {
    const int l = t & 63, w = t >> 6;
    const int lr = l & 15, lq = l >> 4;
    const int r0 = (bid - 4096) * 128;
    const int b  = r0 >> 12;
    const int hw0 = r0 & 4095;

    {
      const float4* w4 = (const float4*)w_off;
      #pragma unroll
      for (int j = 0; j < 12; ++j) {
        int m = t + j * 256;
        int col = m >> 5, ch = m & 31;
        float4 lo = w4[m * 2];
        float4 hi = w4[m * 2 + 1];
        u32x4 v;
        v.x = (u32)f2bf(lo.x) | ((u32)f2bf(lo.y) << 16);
        v.y = (u32)f2bf(lo.z) | ((u32)f2bf(lo.w) << 16);
        v.z = (u32)f2bf(hi.x) | ((u32)f2bf(hi.y) << 16);
        v.w = (u32)f2bf(hi.z) | ((u32)f2bf(hi.w) << 16);
        int slot = (col << 5) | (ch ^ (col & 7));
        *(u32x4*)(smem + slot * 16) = v;
      }
    }

    f32x4 acc[2][6];
    #pragma unroll
    for (int m = 0; m < 2; ++m)
      #pragma unroll
      for (int n = 0; n < 6; ++n)
        acc[m][n] = (f32x4){0.f, 0.f, 0.f, 0.f};

    for (int step = 0; step < 8; ++step) {
      const int k0 = step * 32;
      #pragma unroll
      for (int it = 0; it < 8; ++it) {
        int idx = t + it * 256;
        int i = idx & 127;
        int p = idx >> 7;
        const float* src = query + ((size_t)(b * 256 + k0 + 2 * p)) * 4096 + hw0 + i;
        u32 v = (u32)f2bf(src[0]) | ((u32)f2bf(src[4096]) << 16);
        *(u32*)(smem + 49152 + ((p >> 2) * 128 + i) * 16 + (p & 3) * 4) = v;
      }
      __syncthreads();

      const int chb = step * 4 + lq;
      bf16x8 bfr[6], af[2];
      #pragma unroll
      for (int n = 0; n < 6; ++n) {
        int col = n * 16 + lr;
        bfr[n] = *(const bf16x8*)(smem + ((col << 5) | (chb ^ (col & 7))) * 16);
      }
      #pragma unroll
      for (int m = 0; m < 2; ++m)
        af[m] = *(const bf16x8*)(smem + 49152 + (lq * 128 + w * 32 + m * 16 + lr) * 16);

      #pragma unroll
      for (int m = 0; m < 2; ++m)
        #pragma unroll
        for (int n = 0; n < 6; ++n)
          acc[m][n] = __builtin_amdgcn_mfma_f32_16x16x32_bf16(af[m], bfr[n], acc[m][n], 0, 0, 0);
      __syncthreads();
    }

    float* epi = (float*)smem;
    #pragma unroll
    for (int n = 0; n < 6; ++n) {
      int o = n * 16 + lr;
      float bo = b_off[o];
      #pragma unroll
      for (int m = 0; m < 2; ++m) {
        int row = w * 32 + m * 16 + lq * 4;
        #pragma unroll
        for (int r = 0; r < 4; ++r)
          epi[(row + r) * 98 + o] = acc[m][n][r] + bo;
      }
    }
    __syncthreads();

    #pragma unroll
    for (int k = 0; k < 4; ++k) {
      int task = t + k * 256;
      int row = task & 127, head = task >> 7;
      const float* o = epi + row * 98 + head * 12;
      float ox[NP_], oy[NP_], lg[NP_];
      #pragma unroll
      for (int p = 0; p < NP_; ++p) {
        ox[p] = o[p * 3 + 0];
        oy[p] = o[p * 3 + 1];
        lg[p] = o[p * 3 + 2];
      }
      float mx = fmaxf(fmaxf(lg[0], lg[1]), fmaxf(lg[2], lg[3]));
      float e[NP_];
      float s = 0.f;
      #pragma unroll
      for (int p = 0; p < NP_; ++p) { e[p] = expf(lg[p] - mx); s += e[p]; }
      float inv = 1.f / s;

      int hw = (r0 + row) & 4095;
      float wq = (float)(hw & 63);
      float hq = (float)(hw >> 6);
      float4* dst = params + ((size_t)(b * NH_ + head) * HW_ + hw) * NP_;
      #pragma unroll
      for (int p = 0; p < NP_; ++p) {
        dst[p] = make_float4(wq + ox[p] * 3.15f, hq + oy[p] * 3.15f, e[p] * inv, 0.f);
      }
    }
  } else {
    int i = (bid - 4352) * 256 + t;
    float4 v = ((const float4*)w_proj)[i];
    uint2 o;
    o.x = (u32)f2bf(v.x) | ((u32)f2bf(v.y) << 16);
    o.y = (u32)f2bf(v.z) | ((u32)f2bf(v.w) << 16);
    wproj_bf[i] = o;
  }
}

// ---------------------------------------------------------------------------
// Kernel 2: fused sample + projection, 16-row tiles (2048 blocks).
// Phase 1: bilinear-sample into LDS A layout [kc 0..31][row 0..15] 16B slots.
// Phase 2: GEMM 16x256x256, double-buffered B chunks: issue next chunk's
//   global_load_lds BEFORE computing current chunk; ONE barrier per chunk
//   (its vmcnt drain lands the prefetch). Wave w covers 64 cols.
// LDS: A 8KB + 2 x 16KB B = 40KB.
// ---------------------------------------------------------------------------
__global__ __launch_bounds__(256) void k_fused(const float4* __restrict__ params,
                                               const u32* __restrict__ key_t2,
                                               const u16* __restrict__ Bw,
                                               const float* __restrict__ bias,
                                               float* __restrict__ out) {
  __shared__ char smem[40960];  // A: [0,8K)  B0: [8K,24K)  B1: [24K,40K)
  const int t = threadIdx.x, l = t & 63, w = t >> 6;
  const int lr = l & 15, lq = l >> 4;
  const int r0 = blockIdx.x * 16;
  const int b = r0 >> 12;
  const int hw0 = r0 & 4095;

  // ---- Phase 1: sampling (validated dp-lane mapping) ----
  {
    const int dp   = t & 15;
    const int head = (t >> 4) & 7;
    const int rsub = t >> 7;           // 0..1
    const int g = b * NH_ + head;
    const u32* kg = key_t2 + ((size_t)g << 16) + dp;
    const int kc = head * 4 + (dp >> 2);
    const int word = (dp & 3) * 4;

    #pragma unroll
    for (int it = 0; it < 8; ++it) {
      int row = it * 2 + rsub;
      int hw = hw0 + row;
      const float4* pp = params + (((size_t)g << 12) + hw) * NP_;

      float a0 = 0.f, a1 = 0.f;
      #pragma unroll
      for (int p = 0; p < NP_; ++p) {
        float4 pr = pp[p];
        float x = pr.x, y = pr.y, wt = pr.z;
        float x0f = floorf(x), y0f = floorf(y);
        int ix0 = (int)x0f, iy0 = (int)y0f;
        int ix1 = ix0 + 1, iy1 = iy0 + 1;
        float fx = x - x0f, fy = y - y0f;
        float gx0 = 1.f - fx, gy0 = 1.f - fy;

        bool vx0 = (ix0 >= 0) & (ix0 <= W_ - 1);
        bool vx1 = (ix1 >= 0) & (ix1 <= W_ - 1);
        bool vy0 = (iy0 >= 0) & (iy0 <= H_ - 1);
        bool vy1 = (iy1 >= 0) & (iy1 <= H_ - 1);
        int cx0 = min(max(ix0, 0), W_ - 1), cx1 = min(max(ix1, 0), W_ - 1);
        int cy0 = min(max(iy0, 0), H_ - 1), cy1 = min(max(iy1, 0), H_ - 1);

        u32 v00 = kg[(cy0 * W_ + cx0) * 16];
        u32 v01 = kg[(cy0 * W_ + cx1) * 16];
        u32 v10 = kg[(cy1 * W_ + cx0) * 16];
        u32 v11 = kg[(cy1 * W_ + cx1) * 16];

        float w00 = gx0 * gy0 * ((vx0 & vy0) ? 1.f : 0.f);
        float w01 = fx  * gy0 * ((vx1 & vy0) ? 1.f : 0.f);
        float w10 = gx0 * fy  * ((vx0 & vy1) ? 1.f : 0.f);
        float w11 = fx  * fy  * ((vx1 & vy1) ? 1.f : 0.f);

        a0 = fmaf(wt, w00 * bflo(v00) + w01 * bflo(v01) + w10 * bflo(v10) + w11 * bflo(v11), a0);
        a1 = fmaf(wt, w00 * bfhi(v00) + w01 * bfhi(v01) + w10 * bfhi(v10) + w11 * bfhi(v11), a1);
      }
      *(u32*)(smem + (kc * 16 + row) * 16 + word) = (u32)f2bf(a0) | ((u32)f2bf(a1) << 16);
    }
  }

  // ---- Phase 2: GEMM (16 x 256) with double-buffered B prefetch ----
  f32x4 acc[4];
  #pragma unroll
  for (int n = 0; n < 4; ++n) acc[n] = (f32x4){0.f, 0.f, 0.f, 0.f};

  // stage B chunk c into buffer buf: slots [kq 0..3][col 0..255]
  #define STAGE_B(c, buf)                                                         \
    {                                                                             \
      const int k0s = (c) * 32;                                                   \
      _Pragma("unroll")                                                           \
      for (int j = 0; j < 4; ++j) {                                               \
        int i = w * 4 + j;                                                        \
        int kq = i >> 2, cg = i & 3;                                              \
        const u16* gsrc = Bw + ((size_t)(cg * 64 + l)) * 256 + k0s + kq * 8;      \
        __builtin_amdgcn_global_load_lds((const as1_u32*)gsrc,                    \
            (as3_u32*)(smem + 8192 + (buf) * 16384 + (kq * 256 + cg * 64) * 16),  \
            16, 0, 0);                                                            \
      }                                                                           \
    }

  STAGE_B(0, 0);
  __syncthreads();   // chunk0 landed; also guards phase-1 A writes

  #pragma unroll
  for (int c = 0; c < 8; ++c) {
    if (c < 7) STAGE_B(c + 1, (c + 1) & 1);   // issue next; lands in other buffer

    const int base = 8192 + (c & 1) * 16384;
    const int kc = c * 4 + lq;
    bf16x8 af = *(const bf16x8*)(smem + (kc * 16 + lr) * 16);
    #pragma unroll
    for (int n = 0; n < 4; ++n) {
      bf16x8 bfr = *(const bf16x8*)(smem + base + (lq * 256 + w * 64 + n * 16 + lr) * 16);
      acc[n] = __builtin_amdgcn_mfma_f32_16x16x32_bf16(af, bfr, acc[n], 0, 0, 0);
    }
    __syncthreads();  // drains prefetch (vmcnt 0) + syncs buffer swap
  }
  #undef STAGE_B

  // ---- epilogue ----
  #pragma unroll
  for (int n = 0; n < 4; ++n) {
    int col = w * 64 + n * 16 + lr;
    float bv = bias[col];
    int row = r0 + lq * 4;
    #pragma unroll
    for (int r = 0; r < 4; ++r)
      out[(size_t)(row + r) * 256 + col] = acc[n][r] + bv;
  }
}

// ---------------------------------------------------------------------------
extern "C" void kernel_launch(void* const* d_in, const int* in_sizes, int n_in,
                              void* d_out, int out_size, void* d_ws, size_t ws_size,
                              hipStream_t stream) {
  const float* query  = (const float*)d_in[0];
  const float* key    = (const float*)d_in[1];
  const float* w_off  = (const float*)d_in[2];
  const float* b_off  = (const float*)d_in[3];
  const float* w_proj = (const float*)d_in[4];
  const float* b_proj = (const float*)d_in[5];
  float* out = (float*)d_out;

  char* ws = (char*)d_ws;
  float4* params   = (float4*)ws;                               // 16 MB
  u32*    key_t2   = (u32*)(ws + (size_t)16 * 1024 * 1024);     // 16 MB
  uint2*  wproj_bf = (uint2*)(ws + (size_t)32 * 1024 * 1024);   // 128 KB

  hipLaunchKernelGGL(k_prep,  dim3(4416), dim3(256), 0, stream,
                     query, key, w_off, b_off, w_proj, params, key_t2, wproj_bf);
  hipLaunchKernelGGL(k_fused, dim3(2048), dim3(256), 0, stream,
                     params, key_t2, (const u16*)wproj_bf, b_proj, out);
}

// Round 8
// 73.390 us; speedup vs baseline: 1.2571x; 1.2571x over previous
//
#include <hip/hip_runtime.h>
#include <cstdint>

#define B_   8
#define C_   256
#define H_   64
#define W_   64
#define HW_  4096
#define NH_  8
#define NP_  4
#define DH_  32

typedef unsigned int u32;
typedef unsigned short u16;
typedef __attribute__((ext_vector_type(8))) short bf16x8;
typedef __attribute__((ext_vector_type(4))) float f32x4;
typedef __attribute__((ext_vector_type(4))) u32 u32x4;
typedef __attribute__((address_space(3))) u32 as3_u32;
typedef __attribute__((address_space(1))) u32 as1_u32;

__device__ __forceinline__ u16 f2bf(float f) {
  u32 u = __builtin_bit_cast(u32, f);
  return (u16)((u + 0x7FFFu + ((u >> 16) & 1u)) >> 16);
}
__device__ __forceinline__ float bflo(u32 v) { return __builtin_bit_cast(float, v << 16); }
__device__ __forceinline__ float bfhi(u32 v) { return __builtin_bit_cast(float, v & 0xFFFF0000u); }

// ---------------------------------------------------------------------------
// Kernel 1: merged prep. blocks [0,4096): key transpose->bf16;
// [4096,4352): offsets MFMA GEMM + softmax + bilinear-weight precompute;
// [4352,4416): w_proj->bf16.
// Emits per (g,hw,p): wts4 = wt*(w00,w01,w10,w11) f32x4 (validity-zeroed),
//                     idx4 = cx0 | cx1<<6 | cy0<<12 | cy1<<18.
// ---------------------------------------------------------------------------
__global__ __launch_bounds__(256) void k_prep(const float* __restrict__ query,
                                              const float* __restrict__ key,
                                              const float* __restrict__ w_off,
                                              const float* __restrict__ b_off,
                                              const float* __restrict__ w_proj,
                                              float4* __restrict__ wts4,
                                              u32* __restrict__ idx4,
                                              u32* __restrict__ key_t2,
                                              uint2* __restrict__ wproj_bf) {
  __shared__ char smem[57344];
  const int bid = blockIdx.x;
  const int t = threadIdx.x;

  if (bid < 4096) {
    // ---- transpose key (G, DH, HW) -> key_t2 (G, HW, 16 u32) ----
    float* tile = (float*)smem;  // 32 x 65
    const int g = bid >> 6;
    const int hw0 = (bid & 63) << 6;
    const float* kg = key + (size_t)g * DH_ * HW_ + hw0;
    #pragma unroll
    for (int k = 0; k < 8; ++k) {
      int idx = t + k * 256;
      int d = idx >> 6, j = idx & 63;
      tile[d * 65 + j] = kg[d * HW_ + j];
    }
    __syncthreads();
    u32* kt = key_t2 + ((size_t)g * HW_ + hw0) * 16;
    #pragma unroll
    for (int k = 0; k < 4; ++k) {
      int idx = t + k * 256;
      int j = idx >> 4, dp = idx & 15;
      u32 v = (u32)f2bf(tile[(2 * dp) * 65 + j]) | ((u32)f2bf(tile[(2 * dp + 1) * 65 + j]) << 16);
      kt[j * 16 + dp] = v;
    }
  } else if (bid < 4352) {
    // ---- offsets GEMM (bf16 MFMA) + softmax + weight precompute ----
    const int l = t & 63, w = t >> 6;
    const int lr = l & 15, lq = l >> 4;
    const int r0 = (bid - 4096) * 128;
    const int b  = r0 >> 12;
    const int hw0 = r0 & 4095;

    {
      const float4* w4 = (const float4*)w_off;
      #pragma unroll
      for (int j = 0; j < 12; ++j) {
        int m = t + j * 256;
        int col = m >> 5, ch = m & 31;
        float4 lo = w4[m * 2];
        float4 hi = w4[m * 2 + 1];
        u32x4 v;
        v.x = (u32)f2bf(lo.x) | ((u32)f2bf(lo.y) << 16);
        v.y = (u32)f2bf(lo.z) | ((u32)f2bf(lo.w) << 16);
        v.z = (u32)f2bf(hi.x) | ((u32)f2bf(hi.y) << 16);
        v.w = (u32)f2bf(hi.z) | ((u32)f2bf(hi.w) << 16);
        int slot = (col << 5) | (ch ^ (col & 7));
        *(u32x4*)(smem + slot * 16) = v;
      }
    }

    f32x4 acc[2][6];
    #pragma unroll
    for (int m = 0; m < 2; ++m)
      #pragma unroll
      for (int n = 0; n < 6; ++n)
        acc[m][n] = (f32x4){0.f, 0.f, 0.f, 0.f};

    for (int step = 0; step < 8; ++step) {
      const int k0 = step * 32;
      #pragma unroll
      for (int it = 0; it < 8; ++it) {
        int idx = t + it * 256;
        int i = idx & 127;
        int p = idx >> 7;
        const float* src = query + ((size_t)(b * 256 + k0 + 2 * p)) * 4096 + hw0 + i;
        u32 v = (u32)f2bf(src[0]) | ((u32)f2bf(src[4096]) << 16);
        *(u32*)(smem + 49152 + ((p >> 2) * 128 + i) * 16 + (p & 3) * 4) = v;
      }
      __syncthreads();

      const int chb = step * 4 + lq;
      bf16x8 bfr[6], af[2];
      #pragma unroll
      for (int n = 0; n < 6; ++n) {
        int col = n * 16 + lr;
        bfr[n] = *(const bf16x8*)(smem + ((col << 5) | (chb ^ (col & 7))) * 16);
      }
      #pragma unroll
      for (int m = 0; m < 2; ++m)
        af[m] = *(const bf16x8*)(smem + 49152 + (lq * 128 + w * 32 + m * 16 + lr) * 16);

      #pragma unroll
      for (int m = 0; m < 2; ++m)
        #pragma unroll
        for (int n = 0; n < 6; ++n)
          acc[m][n] = __builtin_amdgcn_mfma_f32_16x16x32_bf16(af[m], bfr[n], acc[m][n], 0, 0, 0);
      __syncthreads();
    }

    float* epi = (float*)smem;
    #pragma unroll
    for (int n = 0; n < 6; ++n) {
      int o = n * 16 + lr;
      float bo = b_off[o];
      #pragma unroll
      for (int m = 0; m < 2; ++m) {
        int row = w * 32 + m * 16 + lq * 4;
        #pragma unroll
        for (int r = 0; r < 4; ++r)
          epi[(row + r) * 98 + o] = acc[m][n][r] + bo;
      }
    }
    __syncthreads();

    #pragma unroll
    for (int k = 0; k < 4; ++k) {
      int task = t + k * 256;
      int row = task & 127, head = task >> 7;
      const float* o = epi + row * 98 + head * 12;
      float ox[NP_], oy[NP_], lg[NP_];
      #pragma unroll
      for (int p = 0; p < NP_; ++p) {
        ox[p] = o[p * 3 + 0];
        oy[p] = o[p * 3 + 1];
        lg[p] = o[p * 3 + 2];
      }
      float mx = fmaxf(fmaxf(lg[0], lg[1]), fmaxf(lg[2], lg[3]));
      float e[NP_];
      float s = 0.f;
      #pragma unroll
      for (int p = 0; p < NP_; ++p) { e[p] = expf(lg[p] - mx); s += e[p]; }
      float inv = 1.f / s;

      int hw = (r0 + row) & 4095;
      float wq = (float)(hw & 63);
      float hq = (float)(hw >> 6);
      size_t base = ((size_t)(b * NH_ + head) * HW_ + hw) * NP_;
      #pragma unroll
      for (int p = 0; p < NP_; ++p) {
        float wt = e[p] * inv;
        float x = wq + ox[p] * 3.15f;
        float y = hq + oy[p] * 3.15f;
        float x0f = floorf(x), y0f = floorf(y);
        int ix0 = (int)x0f, iy0 = (int)y0f;
        int ix1 = ix0 + 1, iy1 = iy0 + 1;
        float fx = x - x0f, fy = y - y0f;
        float gx0 = 1.f - fx, gy0 = 1.f - fy;

        bool vx0 = (ix0 >= 0) & (ix0 <= W_ - 1);
        bool vx1 = (ix1 >= 0) & (ix1 <= W_ - 1);
        bool vy0 = (iy0 >= 0) & (iy0 <= H_ - 1);
        bool vy1 = (iy1 >= 0) & (iy1 <= H_ - 1);
        int cx0 = min(max(ix0, 0), W_ - 1), cx1 = min(max(ix1, 0), W_ - 1);
        int cy0 = min(max(iy0, 0), H_ - 1), cy1 = min(max(iy1, 0), H_ - 1);

        float4 ww;
        ww.x = wt * gx0 * gy0 * ((vx0 & vy0) ? 1.f : 0.f);
        ww.y = wt * fx  * gy0 * ((vx1 & vy0) ? 1.f : 0.f);
        ww.z = wt * gx0 * fy  * ((vx0 & vy1) ? 1.f : 0.f);
        ww.w = wt * fx  * fy  * ((vx1 & vy1) ? 1.f : 0.f);
        wts4[base + p] = ww;
        idx4[base + p] = (u32)cx0 | ((u32)cx1 << 6) | ((u32)cy0 << 12) | ((u32)cy1 << 18);
      }
    }
  } else {
    // ---- convert w_proj to bf16 pairs ----
    int i = (bid - 4352) * 256 + t;
    float4 v = ((const float4*)w_proj)[i];
    uint2 o;
    o.x = (u32)f2bf(v.x) | ((u32)f2bf(v.y) << 16);
    o.y = (u32)f2bf(v.z) | ((u32)f2bf(v.w) << 16);
    wproj_bf[i] = o;
  }
}

// ---------------------------------------------------------------------------
// Kernel 2: bilinear gather + weighted sum using precomputed weights/indices.
// 2 channels/thread, no LDS, max occupancy. Block = 2 hw x 128 channel-pairs.
// ---------------------------------------------------------------------------
__global__ __launch_bounds__(256) void k_sample(const float4* __restrict__ wts4,
                                                const u32* __restrict__ idx4,
                                                const u32* __restrict__ key_t2,
                                                u32* __restrict__ feat2) {
  const int t = threadIdx.x;
  const int hwid = blockIdx.x * 2 + (t >> 7);
  const int b = hwid >> 12;
  const int hw = hwid & 4095;
  const int c2 = t & 127;
  const int head = c2 >> 4, dp = c2 & 15;
  const int g = b * NH_ + head;
  const size_t pbase = (((size_t)g << 12) + hw) * NP_;
  const u32* kg = key_t2 + ((size_t)g << 16) + dp;

  // hoist all params loads; then all 16 gathers can be in flight
  float4 W[NP_];
  u32 I[NP_];
  #pragma unroll
  for (int p = 0; p < NP_; ++p) { W[p] = wts4[pbase + p]; I[p] = idx4[pbase + p]; }

  u32 v00[NP_], v01[NP_], v10[NP_], v11[NP_];
  #pragma unroll
  for (int p = 0; p < NP_; ++p) {
    u32 ip = I[p];
    int cx0 = ip & 63, cx1 = (ip >> 6) & 63, cy0 = (ip >> 12) & 63, cy1 = (ip >> 18) & 63;
    v00[p] = kg[((cy0 << 6) | cx0) * 16];
    v01[p] = kg[((cy0 << 6) | cx1) * 16];
    v10[p] = kg[((cy1 << 6) | cx0) * 16];
    v11[p] = kg[((cy1 << 6) | cx1) * 16];
  }

  float a0 = 0.f, a1 = 0.f;
  #pragma unroll
  for (int p = 0; p < NP_; ++p) {
    a0 = fmaf(W[p].x, bflo(v00[p]), a0);
    a0 = fmaf(W[p].y, bflo(v01[p]), a0);
    a0 = fmaf(W[p].z, bflo(v10[p]), a0);
    a0 = fmaf(W[p].w, bflo(v11[p]), a0);
    a1 = fmaf(W[p].x, bfhi(v00[p]), a1);
    a1 = fmaf(W[p].y, bfhi(v01[p]), a1);
    a1 = fmaf(W[p].z, bfhi(v10[p]), a1);
    a1 = fmaf(W[p].w, bfhi(v11[p]), a1);
  }
  feat2[((size_t)b * HW_ + hw) * 128 + c2] = (u32)f2bf(a0) | ((u32)f2bf(a1) << 16);
}

// ---------------------------------------------------------------------------
// Kernel 3: out = feat @ w_proj^T + b_proj via bf16 MFMA (round-2 validated).
// ---------------------------------------------------------------------------
__global__ __launch_bounds__(256) void k_proj_mfma(const u16* __restrict__ A,
                                                   const u16* __restrict__ Bw,
                                                   const float* __restrict__ bias,
                                                   float* __restrict__ out) {
  __shared__ char smem[16384];
  const int t = threadIdx.x, w = t >> 6, l = t & 63;
  const int wm = w >> 1, wn = w & 1;
  const int bid = blockIdx.x;
  const int nb = bid & 1, mb = bid >> 1;
  const int r0 = mb * 128, n0 = nb * 128;

  f32x4 acc[4][4];
  #pragma unroll
  for (int m = 0; m < 4; ++m)
    #pragma unroll
    for (int n = 0; n < 4; ++n)
      acc[m][n] = (f32x4){0.f, 0.f, 0.f, 0.f};

  for (int k0 = 0; k0 < 256; k0 += 32) {
    if (w < 2) {
      #pragma unroll
      for (int j = 0; j < 4; ++j) {
        int i = w * 4 + j;
        int kq = i >> 1, half = i & 1;
        const u16* g = A + ((size_t)(r0 + half * 64 + l)) * 256 + k0 + kq * 8;
        __builtin_amdgcn_global_load_lds((const as1_u32*)g, (as3_u32*)(smem + i * 1024), 16, 0, 0);
      }
    } else {
      #pragma unroll
      for (int j = 0; j < 4; ++j) {
        int i = (w - 2) * 4 + j;
        int kq = i >> 1, half = i & 1;
        const u16* g = Bw + ((size_t)(n0 + half * 64 + l)) * 256 + k0 + kq * 8;
        __builtin_amdgcn_global_load_lds((const as1_u32*)g, (as3_u32*)(smem + 8192 + i * 1024), 16, 0, 0);
      }
    }
    __syncthreads();

    const int kq = l >> 4, lr = l & 15;
    bf16x8 af[4], bfr[4];
    #pragma unroll
    for (int m = 0; m < 4; ++m)
      af[m] = *(const bf16x8*)(smem + (kq * 128 + wm * 64 + m * 16 + lr) * 16);
    #pragma unroll
    for (int n = 0; n < 4; ++n)
      bfr[n] = *(const bf16x8*)(smem + 8192 + (kq * 128 + wn * 64 + n * 16 + lr) * 16);
    #pragma unroll
    for (int m = 0; m < 4; ++m)
      #pragma unroll
      for (int n = 0; n < 4; ++n)
        acc[m][n] = __builtin_amdgcn_mfma_f32_16x16x32_bf16(af[m], bfr[n], acc[m][n], 0, 0, 0);
    __syncthreads();
  }

  const int lr = l & 15, lq = l >> 4;
  #pragma unroll
  for (int n = 0; n < 4; ++n) {
    int col = n0 + wn * 64 + n * 16 + lr;
    float bv = bias[col];
    #pragma unroll
    for (int m = 0; m < 4; ++m) {
      int row = r0 + wm * 64 + m * 16 + lq * 4;
      #pragma unroll
      for (int r = 0; r < 4; ++r)
        out[(size_t)(row + r) * 256 + col] = acc[m][n][r] + bv;
    }
  }
}

// ---------------------------------------------------------------------------
extern "C" void kernel_launch(void* const* d_in, const int* in_sizes, int n_in,
                              void* d_out, int out_size, void* d_ws, size_t ws_size,
                              hipStream_t stream) {
  const float* query  = (const float*)d_in[0];
  const float* key    = (const float*)d_in[1];
  const float* w_off  = (const float*)d_in[2];
  const float* b_off  = (const float*)d_in[3];
  const float* w_proj = (const float*)d_in[4];
  const float* b_proj = (const float*)d_in[5];
  float* out = (float*)d_out;

  char* ws = (char*)d_ws;
  float4* wts4     = (float4*)ws;                               // 16 MB
  u32*    key_t2   = (u32*)(ws + (size_t)16 * 1024 * 1024);     // 16 MB
  u32*    idx4     = (u32*)(ws + (size_t)32 * 1024 * 1024);     //  4 MB
  u32*    feat2    = (u32*)(ws + (size_t)36 * 1024 * 1024);     // 16 MB
  uint2*  wproj_bf = (uint2*)(ws + (size_t)52 * 1024 * 1024);   // 128 KB

  hipLaunchKernelGGL(k_prep,      dim3(4416),  dim3(256), 0, stream,
                     query, key, w_off, b_off, w_proj, wts4, idx4, key_t2, wproj_bf);
  hipLaunchKernelGGL(k_sample,    dim3(16384), dim3(256), 0, stream,
                     wts4, idx4, key_t2, feat2);
  hipLaunchKernelGGL(k_proj_mfma, dim3(512),   dim3(256), 0, stream,
                     (const u16*)feat2, (const u16*)wproj_bf, b_proj, out);
}

// Round 9
// 71.820 us; speedup vs baseline: 1.2846x; 1.0219x over previous
//
#include <hip/hip_runtime.h>
#include <cstdint>

#define B_   8
#define C_   256
#define H_   64
#define W_   64
#define HW_  4096
#define NH_  8
#define NP_  4
#define DH_  32

typedef unsigned int u32;
typedef unsigned short u16;
typedef __attribute__((ext_vector_type(8))) short bf16x8;
typedef __attribute__((ext_vector_type(4))) float f32x4;
typedef __attribute__((ext_vector_type(4))) u32 u32x4;
typedef __attribute__((address_space(3))) u32 as3_u32;
typedef __attribute__((address_space(1))) u32 as1_u32;

__device__ __forceinline__ u16 f2bf(float f) {
  u32 u = __builtin_bit_cast(u32, f);
  return (u16)((u + 0x7FFFu + ((u >> 16) & 1u)) >> 16);
}
__device__ __forceinline__ float bflo(u32 v) { return __builtin_bit_cast(float, v << 16); }
__device__ __forceinline__ float bfhi(u32 v) { return __builtin_bit_cast(float, v & 0xFFFF0000u); }

// ---------------------------------------------------------------------------
// Kernel 1a: key transpose -> bf16 (8.3KB LDS, high occupancy) + w_proj convert.
// blocks [0,4096): transpose; [4096,4160): w_proj->bf16.
// ---------------------------------------------------------------------------
__global__ __launch_bounds__(256) void k_trans_conv(const float* __restrict__ key,
                                                    const float* __restrict__ w_proj,
                                                    u32* __restrict__ key_t2,
                                                    uint2* __restrict__ wproj_bf) {
  __shared__ float tile[32 * 65];
  const int bid = blockIdx.x;
  const int t = threadIdx.x;

  if (bid < 4096) {
    const int g = bid >> 6;
    const int hw0 = (bid & 63) << 6;
    const float* kg = key + (size_t)g * DH_ * HW_ + hw0;
    #pragma unroll
    for (int k = 0; k < 8; ++k) {
      int idx = t + k * 256;
      int d = idx >> 6, j = idx & 63;
      tile[d * 65 + j] = kg[d * HW_ + j];
    }
    __syncthreads();
    u32* kt = key_t2 + ((size_t)g * HW_ + hw0) * 16;
    #pragma unroll
    for (int k = 0; k < 4; ++k) {
      int idx = t + k * 256;
      int j = idx >> 4, dp = idx & 15;
      u32 v = (u32)f2bf(tile[(2 * dp) * 65 + j]) | ((u32)f2bf(tile[(2 * dp + 1) * 65 + j]) << 16);
      kt[j * 16 + dp] = v;
    }
  } else {
    int i = (bid - 4096) * 256 + t;
    float4 v = ((const float4*)w_proj)[i];
    uint2 o;
    o.x = (u32)f2bf(v.x) | ((u32)f2bf(v.y) << 16);
    o.y = (u32)f2bf(v.z) | ((u32)f2bf(v.w) << 16);
    wproj_bf[i] = o;
  }
}

// ---------------------------------------------------------------------------
// Kernel 1b: offsets GEMM (bf16 MFMA) + softmax + bilinear-weight precompute.
// 256 blocks, 57KB LDS. Emits per (g,hw,p): wts4 = wt*(w00,w01,w10,w11),
// idx4 = cx0 | cx1<<6 | cy0<<12 | cy1<<18.
// ---------------------------------------------------------------------------
__global__ __launch_bounds__(256) void k_offsets_mfma(const float* __restrict__ query,
                                                      const float* __restrict__ w_off,
                                                      const float* __restrict__ b_off,
                                                      float4* __restrict__ wts4,
                                                      u32* __restrict__ idx4) {
  __shared__ char smem[57344];  // B: [0,48K) ; A: [48K,56K) ; epilogue aliases
  const int t = threadIdx.x, l = t & 63, w = t >> 6;
  const int lr = l & 15, lq = l >> 4;
  const int r0 = blockIdx.x * 128;
  const int b  = r0 >> 12;
  const int hw0 = r0 & 4095;

  {
    const float4* w4 = (const float4*)w_off;
    #pragma unroll
    for (int j = 0; j < 12; ++j) {
      int m = t + j * 256;
      int col = m >> 5, ch = m & 31;
      float4 lo = w4[m * 2];
      float4 hi = w4[m * 2 + 1];
      u32x4 v;
      v.x = (u32)f2bf(lo.x) | ((u32)f2bf(lo.y) << 16);
      v.y = (u32)f2bf(lo.z) | ((u32)f2bf(lo.w) << 16);
      v.z = (u32)f2bf(hi.x) | ((u32)f2bf(hi.y) << 16);
      v.w = (u32)f2bf(hi.z) | ((u32)f2bf(hi.w) << 16);
      int slot = (col << 5) | (ch ^ (col & 7));
      *(u32x4*)(smem + slot * 16) = v;
    }
  }

  f32x4 acc[2][6];
  #pragma unroll
  for (int m = 0; m < 2; ++m)
    #pragma unroll
    for (int n = 0; n < 6; ++n)
      acc[m][n] = (f32x4){0.f, 0.f, 0.f, 0.f};

  for (int step = 0; step < 8; ++step) {
    const int k0 = step * 32;
    #pragma unroll
    for (int it = 0; it < 8; ++it) {
      int idx = t + it * 256;
      int i = idx & 127;
      int p = idx >> 7;
      const float* src = query + ((size_t)(b * 256 + k0 + 2 * p)) * 4096 + hw0 + i;
      u32 v = (u32)f2bf(src[0]) | ((u32)f2bf(src[4096]) << 16);
      *(u32*)(smem + 49152 + ((p >> 2) * 128 + i) * 16 + (p & 3) * 4) = v;
    }
    __syncthreads();

    const int chb = step * 4 + lq;
    bf16x8 bfr[6], af[2];
    #pragma unroll
    for (int n = 0; n < 6; ++n) {
      int col = n * 16 + lr;
      bfr[n] = *(const bf16x8*)(smem + ((col << 5) | (chb ^ (col & 7))) * 16);
    }
    #pragma unroll
    for (int m = 0; m < 2; ++m)
      af[m] = *(const bf16x8*)(smem + 49152 + (lq * 128 + w * 32 + m * 16 + lr) * 16);

    #pragma unroll
    for (int m = 0; m < 2; ++m)
      #pragma unroll
      for (int n = 0; n < 6; ++n)
        acc[m][n] = __builtin_amdgcn_mfma_f32_16x16x32_bf16(af[m], bfr[n], acc[m][n], 0, 0, 0);
    __syncthreads();
  }

  float* epi = (float*)smem;
  #pragma unroll
  for (int n = 0; n < 6; ++n) {
    int o = n * 16 + lr;
    float bo = b_off[o];
    #pragma unroll
    for (int m = 0; m < 2; ++m) {
      int row = w * 32 + m * 16 + lq * 4;
      #pragma unroll
      for (int r = 0; r < 4; ++r)
        epi[(row + r) * 98 + o] = acc[m][n][r] + bo;
    }
  }
  __syncthreads();

  #pragma unroll
  for (int k = 0; k < 4; ++k) {
    int task = t + k * 256;
    int row = task & 127, head = task >> 7;
    const float* o = epi + row * 98 + head * 12;
    float ox[NP_], oy[NP_], lg[NP_];
    #pragma unroll
    for (int p = 0; p < NP_; ++p) {
      ox[p] = o[p * 3 + 0];
      oy[p] = o[p * 3 + 1];
      lg[p] = o[p * 3 + 2];
    }
    float mx = fmaxf(fmaxf(lg[0], lg[1]), fmaxf(lg[2], lg[3]));
    float e[NP_];
    float s = 0.f;
    #pragma unroll
    for (int p = 0; p < NP_; ++p) { e[p] = expf(lg[p] - mx); s += e[p]; }
    float inv = 1.f / s;

    int hw = (r0 + row) & 4095;
    float wq = (float)(hw & 63);
    float hq = (float)(hw >> 6);
    size_t base = ((size_t)(b * NH_ + head) * HW_ + hw) * NP_;
    #pragma unroll
    for (int p = 0; p < NP_; ++p) {
      float wt = e[p] * inv;
      float x = wq + ox[p] * 3.15f;
      float y = hq + oy[p] * 3.15f;
      float x0f = floorf(x), y0f = floorf(y);
      int ix0 = (int)x0f, iy0 = (int)y0f;
      int ix1 = ix0 + 1, iy1 = iy0 + 1;
      float fx = x - x0f, fy = y - y0f;
      float gx0 = 1.f - fx, gy0 = 1.f - fy;

      bool vx0 = (ix0 >= 0) & (ix0 <= W_ - 1);
      bool vx1 = (ix1 >= 0) & (ix1 <= W_ - 1);
      bool vy0 = (iy0 >= 0) & (iy0 <= H_ - 1);
      bool vy1 = (iy1 >= 0) & (iy1 <= H_ - 1);
      int cx0 = min(max(ix0, 0), W_ - 1), cx1 = min(max(ix1, 0), W_ - 1);
      int cy0 = min(max(iy0, 0), H_ - 1), cy1 = min(max(iy1, 0), H_ - 1);

      float4 ww;
      ww.x = wt * gx0 * gy0 * ((vx0 & vy0) ? 1.f : 0.f);
      ww.y = wt * fx  * gy0 * ((vx1 & vy0) ? 1.f : 0.f);
      ww.z = wt * gx0 * fy  * ((vx0 & vy1) ? 1.f : 0.f);
      ww.w = wt * fx  * fy  * ((vx1 & vy1) ? 1.f : 0.f);
      wts4[base + p] = ww;
      idx4[base + p] = (u32)cx0 | ((u32)cx1 << 6) | ((u32)cy0 << 12) | ((u32)cy1 << 18);
    }
  }
}

// ---------------------------------------------------------------------------
// Kernel 2: bilinear gather + weighted sum using precomputed weights/indices.
// 2 channels/thread, no LDS. Block = 2 hw x 128 channel-pairs.
// ---------------------------------------------------------------------------
__global__ __launch_bounds__(256) void k_sample(const float4* __restrict__ wts4,
                                                const u32* __restrict__ idx4,
                                                const u32* __restrict__ key_t2,
                                                u32* __restrict__ feat2) {
  const int t = threadIdx.x;
  const int hwid = blockIdx.x * 2 + (t >> 7);
  const int b = hwid >> 12;
  const int hw = hwid & 4095;
  const int c2 = t & 127;
  const int head = c2 >> 4, dp = c2 & 15;
  const int g = b * NH_ + head;
  const size_t pbase = (((size_t)g << 12) + hw) * NP_;
  const u32* kg = key_t2 + ((size_t)g << 16) + dp;

  float4 W[NP_];
  u32 I[NP_];
  #pragma unroll
  for (int p = 0; p < NP_; ++p) { W[p] = wts4[pbase + p]; I[p] = idx4[pbase + p]; }

  u32 v00[NP_], v01[NP_], v10[NP_], v11[NP_];
  #pragma unroll
  for (int p = 0; p < NP_; ++p) {
    u32 ip = I[p];
    int cx0 = ip & 63, cx1 = (ip >> 6) & 63, cy0 = (ip >> 12) & 63, cy1 = (ip >> 18) & 63;
    v00[p] = kg[((cy0 << 6) | cx0) * 16];
    v01[p] = kg[((cy0 << 6) | cx1) * 16];
    v10[p] = kg[((cy1 << 6) | cx0) * 16];
    v11[p] = kg[((cy1 << 6) | cx1) * 16];
  }

  float a0 = 0.f, a1 = 0.f;
  #pragma unroll
  for (int p = 0; p < NP_; ++p) {
    a0 = fmaf(W[p].x, bflo(v00[p]), a0);
    a0 = fmaf(W[p].y, bflo(v01[p]), a0);
    a0 = fmaf(W[p].z, bflo(v10[p]), a0);
    a0 = fmaf(W[p].w, bflo(v11[p]), a0);
    a1 = fmaf(W[p].x, bfhi(v00[p]), a1);
    a1 = fmaf(W[p].y, bfhi(v01[p]), a1);
    a1 = fmaf(W[p].z, bfhi(v10[p]), a1);
    a1 = fmaf(W[p].w, bfhi(v11[p]), a1);
  }
  feat2[((size_t)b * HW_ + hw) * 128 + c2] = (u32)f2bf(a0) | ((u32)f2bf(a1) << 16);
}

// ---------------------------------------------------------------------------
// Kernel 3: out = feat @ w_proj^T + b_proj via bf16 MFMA (validated).
// ---------------------------------------------------------------------------
__global__ __launch_bounds__(256) void k_proj_mfma(const u16* __restrict__ A,
                                                   const u16* __restrict__ Bw,
                                                   const float* __restrict__ bias,
                                                   float* __restrict__ out) {
  __shared__ char smem[16384];
  const int t = threadIdx.x, w = t >> 6, l = t & 63;
  const int wm = w >> 1, wn = w & 1;
  const int bid = blockIdx.x;
  const int nb = bid & 1, mb = bid >> 1;
  const int r0 = mb * 128, n0 = nb * 128;

  f32x4 acc[4][4];
  #pragma unroll
  for (int m = 0; m < 4; ++m)
    #pragma unroll
    for (int n = 0; n < 4; ++n)
      acc[m][n] = (f32x4){0.f, 0.f, 0.f, 0.f};

  for (int k0 = 0; k0 < 256; k0 += 32) {
    if (w < 2) {
      #pragma unroll
      for (int j = 0; j < 4; ++j) {
        int i = w * 4 + j;
        int kq = i >> 1, half = i & 1;
        const u16* g = A + ((size_t)(r0 + half * 64 + l)) * 256 + k0 + kq * 8;
        __builtin_amdgcn_global_load_lds((const as1_u32*)g, (as3_u32*)(smem + i * 1024), 16, 0, 0);
      }
    } else {
      #pragma unroll
      for (int j = 0; j < 4; ++j) {
        int i = (w - 2) * 4 + j;
        int kq = i >> 1, half = i & 1;
        const u16* g = Bw + ((size_t)(n0 + half * 64 + l)) * 256 + k0 + kq * 8;
        __builtin_amdgcn_global_load_lds((const as1_u32*)g, (as3_u32*)(smem + 8192 + i * 1024), 16, 0, 0);
      }
    }
    __syncthreads();

    const int kq = l >> 4, lr = l & 15;
    bf16x8 af[4], bfr[4];
    #pragma unroll
    for (int m = 0; m < 4; ++m)
      af[m] = *(const bf16x8*)(smem + (kq * 128 + wm * 64 + m * 16 + lr) * 16);
    #pragma unroll
    for (int n = 0; n < 4; ++n)
      bfr[n] = *(const bf16x8*)(smem + 8192 + (kq * 128 + wn * 64 + n * 16 + lr) * 16);
    #pragma unroll
    for (int m = 0; m < 4; ++m)
      #pragma unroll
      for (int n = 0; n < 4; ++n)
        acc[m][n] = __builtin_amdgcn_mfma_f32_16x16x32_bf16(af[m], bfr[n], acc[m][n], 0, 0, 0);
    __syncthreads();
  }

  const int lr = l & 15, lq = l >> 4;
  #pragma unroll
  for (int n = 0; n < 4; ++n) {
    int col = n0 + wn * 64 + n * 16 + lr;
    float bv = bias[col];
    #pragma unroll
    for (int m = 0; m < 4; ++m) {
      int row = r0 + wm * 64 + m * 16 + lq * 4;
      #pragma unroll
      for (int r = 0; r < 4; ++r)
        out[(size_t)(row + r) * 256 + col] = acc[m][n][r] + bv;
    }
  }
}

// ---------------------------------------------------------------------------
extern "C" void kernel_launch(void* const* d_in, const int* in_sizes, int n_in,
                              void* d_out, int out_size, void* d_ws, size_t ws_size,
                              hipStream_t stream) {
  const float* query  = (const float*)d_in[0];
  const float* key    = (const float*)d_in[1];
  const float* w_off  = (const float*)d_in[2];
  const float* b_off  = (const float*)d_in[3];
  const float* w_proj = (const float*)d_in[4];
  const float* b_proj = (const float*)d_in[5];
  float* out = (float*)d_out;

  char* ws = (char*)d_ws;
  float4* wts4     = (float4*)ws;                               // 16 MB
  u32*    key_t2   = (u32*)(ws + (size_t)16 * 1024 * 1024);     // 16 MB
  u32*    idx4     = (u32*)(ws + (size_t)32 * 1024 * 1024);     //  4 MB
  u32*    feat2    = (u32*)(ws + (size_t)36 * 1024 * 1024);     // 16 MB
  uint2*  wproj_bf = (uint2*)(ws + (size_t)52 * 1024 * 1024);   // 128 KB

  hipLaunchKernelGGL(k_trans_conv,  dim3(4160),  dim3(256), 0, stream,
                     key, w_proj, key_t2, wproj_bf);
  hipLaunchKernelGGL(k_offsets_mfma, dim3(256),  dim3(256), 0, stream,
                     query, w_off, b_off, wts4, idx4);
  hipLaunchKernelGGL(k_sample,      dim3(16384), dim3(256), 0, stream,
                     wts4, idx4, key_t2, feat2);
  hipLaunchKernelGGL(k_proj_mfma,   dim3(512),   dim3(256), 0, stream,
                     (const u16*)feat2, (const u16*)wproj_bf, b_proj, out);
}

// Round 10
// 69.797 us; speedup vs baseline: 1.3219x; 1.0290x over previous
//
#include <hip/hip_runtime.h>
#include <cstdint>

#define B_   8
#define C_   256
#define H_   64
#define W_   64
#define HW_  4096
#define NH_  8
#define NP_  4
#define DH_  32

typedef unsigned int u32;
typedef unsigned short u16;
typedef __attribute__((ext_vector_type(8))) short bf16x8;
typedef __attribute__((ext_vector_type(4))) float f32x4;
typedef __attribute__((ext_vector_type(4))) u32 u32x4;
typedef __attribute__((address_space(3))) u32 as3_u32;
typedef __attribute__((address_space(1))) u32 as1_u32;

__device__ __forceinline__ u16 f2bf(float f) {
  u32 u = __builtin_bit_cast(u32, f);
  return (u16)((u + 0x7FFFu + ((u >> 16) & 1u)) >> 16);
}
__device__ __forceinline__ float bflo(u32 v) { return __builtin_bit_cast(float, v << 16); }
__device__ __forceinline__ float bfhi(u32 v) { return __builtin_bit_cast(float, v & 0xFFFF0000u); }

// ---------------------------------------------------------------------------
// Kernel 1a: key transpose -> bf16 (8.3KB LDS, high occupancy) + w_proj convert.
// blocks [0,4096): transpose; [4096,4160): w_proj->bf16.  (validated)
// ---------------------------------------------------------------------------
__global__ __launch_bounds__(256) void k_trans_conv(const float* __restrict__ key,
                                                    const float* __restrict__ w_proj,
                                                    u32* __restrict__ key_t2,
                                                    uint2* __restrict__ wproj_bf) {
  __shared__ float tile[32 * 65];
  const int bid = blockIdx.x;
  const int t = threadIdx.x;

  if (bid < 4096) {
    const int g = bid >> 6;
    const int hw0 = (bid & 63) << 6;
    const float* kg = key + (size_t)g * DH_ * HW_ + hw0;
    #pragma unroll
    for (int k = 0; k < 8; ++k) {
      int idx = t + k * 256;
      int d = idx >> 6, j = idx & 63;
      tile[d * 65 + j] = kg[d * HW_ + j];
    }
    __syncthreads();
    u32* kt = key_t2 + ((size_t)g * HW_ + hw0) * 16;
    #pragma unroll
    for (int k = 0; k < 4; ++k) {
      int idx = t + k * 256;
      int j = idx >> 4, dp = idx & 15;
      u32 v = (u32)f2bf(tile[(2 * dp) * 65 + j]) | ((u32)f2bf(tile[(2 * dp + 1) * 65 + j]) << 16);
      kt[j * 16 + dp] = v;
    }
  } else {
    int i = (bid - 4096) * 256 + t;
    float4 v = ((const float4*)w_proj)[i];
    uint2 o;
    o.x = (u32)f2bf(v.x) | ((u32)f2bf(v.y) << 16);
    o.y = (u32)f2bf(v.z) | ((u32)f2bf(v.w) << 16);
    wproj_bf[i] = o;
  }
}

// ---------------------------------------------------------------------------
// Kernel 1b: offsets GEMM, single-shot A staging.
// 512 blocks x 64 rows; LDS: B 48KB [0,48K) + A 32KB [48K,80K) = 80KB
// -> 2 blocks/CU. Staging = 64 independent coalesced loads/thread (full MLP),
// ONE barrier, then 48 MFMAs/wave from LDS. Epilogue: softmax + bilinear
// weight/index precompute (validated math).
// A LDS: [kc 0..31][row 0..63] 16B slots. B LDS: [col][ch ^ (col&7)] slots.
// ---------------------------------------------------------------------------
__global__ __launch_bounds__(256) void k_offsets_mfma(const float* __restrict__ query,
                                                      const float* __restrict__ w_off,
                                                      const float* __restrict__ b_off,
                                                      float4* __restrict__ wts4,
                                                      u32* __restrict__ idx4) {
  __shared__ char smem[81920];
  const int t = threadIdx.x, l = t & 63, w = t >> 6;
  const int lr = l & 15, lq = l >> 4;
  const int r0 = blockIdx.x * 64;
  const int b  = r0 >> 12;
  const int hw0 = r0 & 4095;

  // ---- B stage: w_off (96x256 f32) -> bf16 swizzled slots ----
  {
    const float4* w4 = (const float4*)w_off;
    #pragma unroll
    for (int j = 0; j < 12; ++j) {
      int m = t + j * 256;               // col*32 + chunk
      int col = m >> 5, ch = m & 31;
      float4 lo = w4[m * 2];
      float4 hi = w4[m * 2 + 1];
      u32x4 v;
      v.x = (u32)f2bf(lo.x) | ((u32)f2bf(lo.y) << 16);
      v.y = (u32)f2bf(lo.z) | ((u32)f2bf(lo.w) << 16);
      v.z = (u32)f2bf(hi.x) | ((u32)f2bf(hi.y) << 16);
      v.w = (u32)f2bf(hi.z) | ((u32)f2bf(hi.w) << 16);
      int slot = (col << 5) | (ch ^ (col & 7));
      *(u32x4*)(smem + slot * 16) = v;
    }
  }

  // ---- A stage: whole 64-row x 256-k tile, transpose-convert, one shot ----
  {
    const float* qb = query + ((size_t)b * 256) * 4096 + hw0;
    #pragma unroll
    for (int it = 0; it < 32; ++it) {
      int idx = t + it * 256;            // 0..8191
      int i = idx & 63;                  // row
      int p = idx >> 6;                  // k-pair 0..127
      const float* src = qb + (size_t)(2 * p) * 4096 + i;
      u32 v = (u32)f2bf(src[0]) | ((u32)f2bf(src[4096]) << 16);
      int kc = p >> 2;
      *(u32*)(smem + 49152 + (kc * 64 + i) * 16 + (p & 3) * 4) = v;
    }
  }
  __syncthreads();

  // ---- MFMA: wave w = rows w*16..w*16+15; acc 1x6 fragments ----
  f32x4 acc[6];
  #pragma unroll
  for (int n = 0; n < 6; ++n) acc[n] = (f32x4){0.f, 0.f, 0.f, 0.f};

  #pragma unroll
  for (int step = 0; step < 8; ++step) {
    const int kc = step * 4 + lq;
    bf16x8 af = *(const bf16x8*)(smem + 49152 + (kc * 64 + w * 16 + lr) * 16);
    #pragma unroll
    for (int n = 0; n < 6; ++n) {
      int col = n * 16 + lr;
      bf16x8 bfr = *(const bf16x8*)(smem + ((col << 5) | (kc ^ (col & 7))) * 16);
      acc[n] = __builtin_amdgcn_mfma_f32_16x16x32_bf16(af, bfr, acc[n], 0, 0, 0);
    }
  }
  __syncthreads();

  // ---- epilogue: acc -> LDS [row][o] (stride 98), + bias ----
  float* epi = (float*)smem;
  #pragma unroll
  for (int n = 0; n < 6; ++n) {
    int o = n * 16 + lr;
    float bo = b_off[o];
    int row = w * 16 + lq * 4;
    #pragma unroll
    for (int r = 0; r < 4; ++r)
      epi[(row + r) * 98 + o] = acc[n][r] + bo;
  }
  __syncthreads();

  // ---- softmax + bilinear weight/index precompute: 64 rows x 8 heads ----
  #pragma unroll
  for (int k = 0; k < 2; ++k) {
    int task = t + k * 256;
    int row = task & 63, head = task >> 6;
    const float* o = epi + row * 98 + head * 12;
    float ox[NP_], oy[NP_], lg[NP_];
    #pragma unroll
    for (int p = 0; p < NP_; ++p) {
      ox[p] = o[p * 3 + 0];
      oy[p] = o[p * 3 + 1];
      lg[p] = o[p * 3 + 2];
    }
    float mx = fmaxf(fmaxf(lg[0], lg[1]), fmaxf(lg[2], lg[3]));
    float e[NP_];
    float s = 0.f;
    #pragma unroll
    for (int p = 0; p < NP_; ++p) { e[p] = expf(lg[p] - mx); s += e[p]; }
    float inv = 1.f / s;

    int hw = (r0 + row) & 4095;
    float wq = (float)(hw & 63);
    float hq = (float)(hw >> 6);
    size_t base = ((size_t)(b * NH_ + head) * HW_ + hw) * NP_;
    #pragma unroll
    for (int p = 0; p < NP_; ++p) {
      float wt = e[p] * inv;
      float x = wq + ox[p] * 3.15f;
      float y = hq + oy[p] * 3.15f;
      float x0f = floorf(x), y0f = floorf(y);
      int ix0 = (int)x0f, iy0 = (int)y0f;
      int ix1 = ix0 + 1, iy1 = iy0 + 1;
      float fx = x - x0f, fy = y - y0f;
      float gx0 = 1.f - fx, gy0 = 1.f - fy;

      bool vx0 = (ix0 >= 0) & (ix0 <= W_ - 1);
      bool vx1 = (ix1 >= 0) & (ix1 <= W_ - 1);
      bool vy0 = (iy0 >= 0) & (iy0 <= H_ - 1);
      bool vy1 = (iy1 >= 0) & (iy1 <= H_ - 1);
      int cx0 = min(max(ix0, 0), W_ - 1), cx1 = min(max(ix1, 0), W_ - 1);
      int cy0 = min(max(iy0, 0), H_ - 1), cy1 = min(max(iy1, 0), H_ - 1);

      float4 ww;
      ww.x = wt * gx0 * gy0 * ((vx0 & vy0) ? 1.f : 0.f);
      ww.y = wt * fx  * gy0 * ((vx1 & vy0) ? 1.f : 0.f);
      ww.z = wt * gx0 * fy  * ((vx0 & vy1) ? 1.f : 0.f);
      ww.w = wt * fx  * fy  * ((vx1 & vy1) ? 1.f : 0.f);
      wts4[base + p] = ww;
      idx4[base + p] = (u32)cx0 | ((u32)cx1 << 6) | ((u32)cy0 << 12) | ((u32)cy1 << 18);
    }
  }
}

// ---------------------------------------------------------------------------
// Kernel 2: bilinear gather + weighted sum using precomputed weights/indices.
// ---------------------------------------------------------------------------
__global__ __launch_bounds__(256) void k_sample(const float4* __restrict__ wts4,
                                                const u32* __restrict__ idx4,
                                                const u32* __restrict__ key_t2,
                                                u32* __restrict__ feat2) {
  const int t = threadIdx.x;
  const int hwid = blockIdx.x * 2 + (t >> 7);
  const int b = hwid >> 12;
  const int hw = hwid & 4095;
  const int c2 = t & 127;
  const int head = c2 >> 4, dp = c2 & 15;
  const int g = b * NH_ + head;
  const size_t pbase = (((size_t)g << 12) + hw) * NP_;
  const u32* kg = key_t2 + ((size_t)g << 16) + dp;

  float4 W[NP_];
  u32 I[NP_];
  #pragma unroll
  for (int p = 0; p < NP_; ++p) { W[p] = wts4[pbase + p]; I[p] = idx4[pbase + p]; }

  u32 v00[NP_], v01[NP_], v10[NP_], v11[NP_];
  #pragma unroll
  for (int p = 0; p < NP_; ++p) {
    u32 ip = I[p];
    int cx0 = ip & 63, cx1 = (ip >> 6) & 63, cy0 = (ip >> 12) & 63, cy1 = (ip >> 18) & 63;
    v00[p] = kg[((cy0 << 6) | cx0) * 16];
    v01[p] = kg[((cy0 << 6) | cx1) * 16];
    v10[p] = kg[((cy1 << 6) | cx0) * 16];
    v11[p] = kg[((cy1 << 6) | cx1) * 16];
  }

  float a0 = 0.f, a1 = 0.f;
  #pragma unroll
  for (int p = 0; p < NP_; ++p) {
    a0 = fmaf(W[p].x, bflo(v00[p]), a0);
    a0 = fmaf(W[p].y, bflo(v01[p]), a0);
    a0 = fmaf(W[p].z, bflo(v10[p]), a0);
    a0 = fmaf(W[p].w, bflo(v11[p]), a0);
    a1 = fmaf(W[p].x, bfhi(v00[p]), a1);
    a1 = fmaf(W[p].y, bfhi(v01[p]), a1);
    a1 = fmaf(W[p].z, bfhi(v10[p]), a1);
    a1 = fmaf(W[p].w, bfhi(v11[p]), a1);
  }
  feat2[((size_t)b * HW_ + hw) * 128 + c2] = (u32)f2bf(a0) | ((u32)f2bf(a1) << 16);
}

// ---------------------------------------------------------------------------
// Kernel 3: out = feat @ w_proj^T + b_proj via bf16 MFMA (validated).
// ---------------------------------------------------------------------------
__global__ __launch_bounds__(256) void k_proj_mfma(const u16* __restrict__ A,
                                                   const u16* __restrict__ Bw,
                                                   const float* __restrict__ bias,
                                                   float* __restrict__ out) {
  __shared__ char smem[16384];
  const int t = threadIdx.x, w = t >> 6, l = t & 63;
  const int wm = w >> 1, wn = w & 1;
  const int bid = blockIdx.x;
  const int nb = bid & 1, mb = bid >> 1;
  const int r0 = mb * 128, n0 = nb * 128;

  f32x4 acc[4][4];
  #pragma unroll
  for (int m = 0; m < 4; ++m)
    #pragma unroll
    for (int n = 0; n < 4; ++n)
      acc[m][n] = (f32x4){0.f, 0.f, 0.f, 0.f};

  for (int k0 = 0; k0 < 256; k0 += 32) {
    if (w < 2) {
      #pragma unroll
      for (int j = 0; j < 4; ++j) {
        int i = w * 4 + j;
        int kq = i >> 1, half = i & 1;
        const u16* g = A + ((size_t)(r0 + half * 64 + l)) * 256 + k0 + kq * 8;
        __builtin_amdgcn_global_load_lds((const as1_u32*)g, (as3_u32*)(smem + i * 1024), 16, 0, 0);
      }
    } else {
      #pragma unroll
      for (int j = 0; j < 4; ++j) {
        int i = (w - 2) * 4 + j;
        int kq = i >> 1, half = i & 1;
        const u16* g = Bw + ((size_t)(n0 + half * 64 + l)) * 256 + k0 + kq * 8;
        __builtin_amdgcn_global_load_lds((const as1_u32*)g, (as3_u32*)(smem + 8192 + i * 1024), 16, 0, 0);
      }
    }
    __syncthreads();

    const int kq = l >> 4, lr = l & 15;
    bf16x8 af[4], bfr[4];
    #pragma unroll
    for (int m = 0; m < 4; ++m)
      af[m] = *(const bf16x8*)(smem + (kq * 128 + wm * 64 + m * 16 + lr) * 16);
    #pragma unroll
    for (int n = 0; n < 4; ++n)
      bfr[n] = *(const bf16x8*)(smem + 8192 + (kq * 128 + wn * 64 + n * 16 + lr) * 16);
    #pragma unroll
    for (int m = 0; m < 4; ++m)
      #pragma unroll
      for (int n = 0; n < 4; ++n)
        acc[m][n] = __builtin_amdgcn_mfma_f32_16x16x32_bf16(af[m], bfr[n], acc[m][n], 0, 0, 0);
    __syncthreads();
  }

  const int lr = l & 15, lq = l >> 4;
  #pragma unroll
  for (int n = 0; n < 4; ++n) {
    int col = n0 + wn * 64 + n * 16 + lr;
    float bv = bias[col];
    #pragma unroll
    for (int m = 0; m < 4; ++m) {
      int row = r0 + wm * 64 + m * 16 + lq * 4;
      #pragma unroll
      for (int r = 0; r < 4; ++r)
        out[(size_t)(row + r) * 256 + col] = acc[m][n][r] + bv;
    }
  }
}

// ---------------------------------------------------------------------------
extern "C" void kernel_launch(void* const* d_in, const int* in_sizes, int n_in,
                              void* d_out, int out_size, void* d_ws, size_t ws_size,
                              hipStream_t stream) {
  const float* query  = (const float*)d_in[0];
  const float* key    = (const float*)d_in[1];
  const float* w_off  = (const float*)d_in[2];
  const float* b_off  = (const float*)d_in[3];
  const float* w_proj = (const float*)d_in[4];
  const float* b_proj = (const float*)d_in[5];
  float* out = (float*)d_out;

  char* ws = (char*)d_ws;
  float4* wts4     = (float4*)ws;                               // 16 MB
  u32*    key_t2   = (u32*)(ws + (size_t)16 * 1024 * 1024);     // 16 MB
  u32*    idx4     = (u32*)(ws + (size_t)32 * 1024 * 1024);     //  4 MB
  u32*    feat2    = (u32*)(ws + (size_t)36 * 1024 * 1024);     // 16 MB
  uint2*  wproj_bf = (uint2*)(ws + (size_t)52 * 1024 * 1024);   // 128 KB

  hipLaunchKernelGGL(k_trans_conv,   dim3(4160),  dim3(256), 0, stream,
                     key, w_proj, key_t2, wproj_bf);
  hipLaunchKernelGGL(k_offsets_mfma, dim3(512),   dim3(256), 0, stream,
                     query, w_off, b_off, wts4, idx4);
  hipLaunchKernelGGL(k_sample,       dim3(16384), dim3(256), 0, stream,
                     wts4, idx4, key_t2, feat2);
  hipLaunchKernelGGL(k_proj_mfma,    dim3(512),   dim3(256), 0, stream,
                     (const u16*)feat2, (const u16*)wproj_bf, b_proj, out);
}

// Round 11
// 63.746 us; speedup vs baseline: 1.4473x; 1.0949x over previous
//
#include <hip/hip_runtime.h>
#include <hip/hip_fp16.h>
#include <cstdint>

#define B_   8
#define C_   256
#define H_   64
#define W_   64
#define HW_  4096
#define NH_  8
#define NP_  4
#define DH_  32

typedef unsigned int u32;
typedef unsigned short u16;
typedef __attribute__((ext_vector_type(8))) short bf16x8;
typedef __attribute__((ext_vector_type(4))) float f32x4;
typedef __attribute__((ext_vector_type(4))) u32 u32x4;
typedef __attribute__((address_space(3))) u32 as3_u32;
typedef __attribute__((address_space(1))) u32 as1_u32;

__device__ __forceinline__ u16 f2bf(float f) {
  u32 u = __builtin_bit_cast(u32, f);
  return (u16)((u + 0x7FFFu + ((u >> 16) & 1u)) >> 16);
}
__device__ __forceinline__ float bflo(u32 v) { return __builtin_bit_cast(float, v << 16); }
__device__ __forceinline__ float bfhi(u32 v) { return __builtin_bit_cast(float, v & 0xFFFF0000u); }

// ---------------------------------------------------------------------------
// Kernel 1a: key transpose -> bf16 + w_proj convert (validated, unchanged).
// ---------------------------------------------------------------------------
__global__ __launch_bounds__(256) void k_trans_conv(const float* __restrict__ key,
                                                    const float* __restrict__ w_proj,
                                                    u32* __restrict__ key_t2,
                                                    uint2* __restrict__ wproj_bf) {
  __shared__ float tile[32 * 65];
  const int bid = blockIdx.x;
  const int t = threadIdx.x;

  if (bid < 4096) {
    const int g = bid >> 6;
    const int hw0 = (bid & 63) << 6;
    const float* kg = key + (size_t)g * DH_ * HW_ + hw0;
    #pragma unroll
    for (int k = 0; k < 8; ++k) {
      int idx = t + k * 256;
      int d = idx >> 6, j = idx & 63;
      tile[d * 65 + j] = kg[d * HW_ + j];
    }
    __syncthreads();
    u32* kt = key_t2 + ((size_t)g * HW_ + hw0) * 16;
    #pragma unroll
    for (int k = 0; k < 4; ++k) {
      int idx = t + k * 256;
      int j = idx >> 4, dp = idx & 15;
      u32 v = (u32)f2bf(tile[(2 * dp) * 65 + j]) | ((u32)f2bf(tile[(2 * dp + 1) * 65 + j]) << 16);
      kt[j * 16 + dp] = v;
    }
  } else {
    int i = (bid - 4096) * 256 + t;
    float4 v = ((const float4*)w_proj)[i];
    uint2 o;
    o.x = (u32)f2bf(v.x) | ((u32)f2bf(v.y) << 16);
    o.y = (u32)f2bf(v.z) | ((u32)f2bf(v.w) << 16);
    wproj_bf[i] = o;
  }
}

// ---------------------------------------------------------------------------
// Kernel 1b: offsets GEMM, single-shot A staging with CONFLICT-FREE b128 writes.
// 512 blocks x 64 rows; LDS: B 48KB [0,48K) + A 32KB [48K,80K).
// A-stage: thread owns slot sid=(kc,i): loads 8 channels (coalesced 256B/wave,
// stride-16KB apart), packs u32x4, ONE ds_write_b128 (16B lane stride -> no
// bank conflicts). Epilogue: softmax + f16-packed bilinear weights + idx.
// ---------------------------------------------------------------------------
__global__ __launch_bounds__(256) void k_offsets_mfma(const float* __restrict__ query,
                                                      const float* __restrict__ w_off,
                                                      const float* __restrict__ b_off,
                                                      uint2* __restrict__ wpk,
                                                      u32* __restrict__ idx4) {
  __shared__ char smem[81920];
  const int t = threadIdx.x, l = t & 63, w = t >> 6;
  const int lr = l & 15, lq = l >> 4;
  const int r0 = blockIdx.x * 64;
  const int b  = r0 >> 12;
  const int hw0 = r0 & 4095;

  // ---- B stage: w_off (96x256 f32) -> bf16 swizzled slots ----
  {
    const float4* w4 = (const float4*)w_off;
    #pragma unroll
    for (int j = 0; j < 12; ++j) {
      int m = t + j * 256;               // col*32 + chunk
      int col = m >> 5, ch = m & 31;
      float4 lo = w4[m * 2];
      float4 hi = w4[m * 2 + 1];
      u32x4 v;
      v.x = (u32)f2bf(lo.x) | ((u32)f2bf(lo.y) << 16);
      v.y = (u32)f2bf(lo.z) | ((u32)f2bf(lo.w) << 16);
      v.z = (u32)f2bf(hi.x) | ((u32)f2bf(hi.y) << 16);
      v.w = (u32)f2bf(hi.z) | ((u32)f2bf(hi.w) << 16);
      int slot = (col << 5) | (ch ^ (col & 7));
      *(u32x4*)(smem + slot * 16) = v;
    }
  }

  // ---- A stage: 2048 slots (kc 0..31 x row 0..63), 8 slots/thread ----
  {
    const float* qb = query + ((size_t)b * 256) * 4096 + hw0;
    #pragma unroll
    for (int s = 0; s < 8; ++s) {
      int sid = t + s * 256;             // kc*64 + i ; wave-uniform kc, i=lane
      int kc = sid >> 6, i = sid & 63;
      const float* src = qb + (size_t)(kc * 8) * 4096 + i;
      u32x4 v;
      #pragma unroll
      for (int m = 0; m < 4; ++m) {
        float c0 = src[(size_t)(2 * m) * 4096];
        float c1 = src[(size_t)(2 * m + 1) * 4096];
        ((u32*)&v)[m] = (u32)f2bf(c0) | ((u32)f2bf(c1) << 16);
      }
      *(u32x4*)(smem + 49152 + sid * 16) = v;   // ds_write_b128, conflict-free
    }
  }
  __syncthreads();

  // ---- MFMA: wave w = rows w*16..w*16+15; acc 1x6 fragments ----
  f32x4 acc[6];
  #pragma unroll
  for (int n = 0; n < 6; ++n) acc[n] = (f32x4){0.f, 0.f, 0.f, 0.f};

  #pragma unroll
  for (int step = 0; step < 8; ++step) {
    const int kc = step * 4 + lq;
    bf16x8 af = *(const bf16x8*)(smem + 49152 + (kc * 64 + w * 16 + lr) * 16);
    #pragma unroll
    for (int n = 0; n < 6; ++n) {
      int col = n * 16 + lr;
      bf16x8 bfr = *(const bf16x8*)(smem + ((col << 5) | (kc ^ (col & 7))) * 16);
      acc[n] = __builtin_amdgcn_mfma_f32_16x16x32_bf16(af, bfr, acc[n], 0, 0, 0);
    }
  }
  __syncthreads();

  // ---- epilogue: acc -> LDS [row][o] (stride 98), + bias ----
  float* epi = (float*)smem;
  #pragma unroll
  for (int n = 0; n < 6; ++n) {
    int o = n * 16 + lr;
    float bo = b_off[o];
    int row = w * 16 + lq * 4;
    #pragma unroll
    for (int r = 0; r < 4; ++r)
      epi[(row + r) * 98 + o] = acc[n][r] + bo;
  }
  __syncthreads();

  // ---- softmax + f16-packed bilinear weight/index: 64 rows x 8 heads ----
  #pragma unroll
  for (int k = 0; k < 2; ++k) {
    int task = t + k * 256;
    int row = task & 63, head = task >> 6;
    const float* o = epi + row * 98 + head * 12;
    float ox[NP_], oy[NP_], lg[NP_];
    #pragma unroll
    for (int p = 0; p < NP_; ++p) {
      ox[p] = o[p * 3 + 0];
      oy[p] = o[p * 3 + 1];
      lg[p] = o[p * 3 + 2];
    }
    float mx = fmaxf(fmaxf(lg[0], lg[1]), fmaxf(lg[2], lg[3]));
    float e[NP_];
    float s = 0.f;
    #pragma unroll
    for (int p = 0; p < NP_; ++p) { e[p] = expf(lg[p] - mx); s += e[p]; }
    float inv = 1.f / s;

    int hw = (r0 + row) & 4095;
    float wq = (float)(hw & 63);
    float hq = (float)(hw >> 6);
    size_t base = ((size_t)(b * NH_ + head) * HW_ + hw) * NP_;
    #pragma unroll
    for (int p = 0; p < NP_; ++p) {
      float wt = e[p] * inv;
      float x = wq + ox[p] * 3.15f;
      float y = hq + oy[p] * 3.15f;
      float x0f = floorf(x), y0f = floorf(y);
      int ix0 = (int)x0f, iy0 = (int)y0f;
      int ix1 = ix0 + 1, iy1 = iy0 + 1;
      float fx = x - x0f, fy = y - y0f;
      float gx0 = 1.f - fx, gy0 = 1.f - fy;

      bool vx0 = (ix0 >= 0) & (ix0 <= W_ - 1);
      bool vx1 = (ix1 >= 0) & (ix1 <= W_ - 1);
      bool vy0 = (iy0 >= 0) & (iy0 <= H_ - 1);
      bool vy1 = (iy1 >= 0) & (iy1 <= H_ - 1);
      int cx0 = min(max(ix0, 0), W_ - 1), cx1 = min(max(ix1, 0), W_ - 1);
      int cy0 = min(max(iy0, 0), H_ - 1), cy1 = min(max(iy1, 0), H_ - 1);

      float w00 = wt * gx0 * gy0 * ((vx0 & vy0) ? 1.f : 0.f);
      float w01 = wt * fx  * gy0 * ((vx1 & vy0) ? 1.f : 0.f);
      float w10 = wt * gx0 * fy  * ((vx0 & vy1) ? 1.f : 0.f);
      float w11 = wt * fx  * fy  * ((vx1 & vy1) ? 1.f : 0.f);

      __half2 h01 = __floats2half2_rn(w00, w01);
      __half2 h23 = __floats2half2_rn(w10, w11);
      uint2 pk;
      pk.x = *(u32*)&h01;
      pk.y = *(u32*)&h23;
      wpk[base + p]  = pk;
      idx4[base + p] = (u32)cx0 | ((u32)cx1 << 6) | ((u32)cy0 << 12) | ((u32)cy1 << 18);
    }
  }
}

// ---------------------------------------------------------------------------
// Kernel 2: bilinear gather + weighted sum (f16-packed weights).
// 2 channels/thread, no LDS. Block = 2 hw x 128 channel-pairs.
// ---------------------------------------------------------------------------
__global__ __launch_bounds__(256) void k_sample(const uint2* __restrict__ wpk,
                                                const u32* __restrict__ idx4,
                                                const u32* __restrict__ key_t2,
                                                u32* __restrict__ feat2) {
  const int t = threadIdx.x;
  const int hwid = blockIdx.x * 2 + (t >> 7);
  const int b = hwid >> 12;
  const int hw = hwid & 4095;
  const int c2 = t & 127;
  const int head = c2 >> 4, dp = c2 & 15;
  const int g = b * NH_ + head;
  const size_t pbase = (((size_t)g << 12) + hw) * NP_;
  const u32* kg = key_t2 + ((size_t)g << 16) + dp;

  uint2 Wp[NP_];
  u32 I[NP_];
  #pragma unroll
  for (int p = 0; p < NP_; ++p) { Wp[p] = wpk[pbase + p]; I[p] = idx4[pbase + p]; }

  u32 v00[NP_], v01[NP_], v10[NP_], v11[NP_];
  #pragma unroll
  for (int p = 0; p < NP_; ++p) {
    u32 ip = I[p];
    int cx0 = ip & 63, cx1 = (ip >> 6) & 63, cy0 = (ip >> 12) & 63, cy1 = (ip >> 18) & 63;
    v00[p] = kg[((cy0 << 6) | cx0) * 16];
    v01[p] = kg[((cy0 << 6) | cx1) * 16];
    v10[p] = kg[((cy1 << 6) | cx0) * 16];
    v11[p] = kg[((cy1 << 6) | cx1) * 16];
  }

  float a0 = 0.f, a1 = 0.f;
  #pragma unroll
  for (int p = 0; p < NP_; ++p) {
    float2 w01 = __half22float2(*(const __half2*)&Wp[p].x);
    float2 w23 = __half22float2(*(const __half2*)&Wp[p].y);
    a0 = fmaf(w01.x, bflo(v00[p]), a0);
    a0 = fmaf(w01.y, bflo(v01[p]), a0);
    a0 = fmaf(w23.x, bflo(v10[p]), a0);
    a0 = fmaf(w23.y, bflo(v11[p]), a0);
    a1 = fmaf(w01.x, bfhi(v00[p]), a1);
    a1 = fmaf(w01.y, bfhi(v01[p]), a1);
    a1 = fmaf(w23.x, bfhi(v10[p]), a1);
    a1 = fmaf(w23.y, bfhi(v11[p]), a1);
  }
  feat2[((size_t)b * HW_ + hw) * 128 + c2] = (u32)f2bf(a0) | ((u32)f2bf(a1) << 16);
}

// ---------------------------------------------------------------------------
// Kernel 3: out = feat @ w_proj^T + b_proj via bf16 MFMA (validated, unchanged).
// ---------------------------------------------------------------------------
__global__ __launch_bounds__(256) void k_proj_mfma(const u16* __restrict__ A,
                                                   const u16* __restrict__ Bw,
                                                   const float* __restrict__ bias,
                                                   float* __restrict__ out) {
  __shared__ char smem[16384];
  const int t = threadIdx.x, w = t >> 6, l = t & 63;
  const int wm = w >> 1, wn = w & 1;
  const int bid = blockIdx.x;
  const int nb = bid & 1, mb = bid >> 1;
  const int r0 = mb * 128, n0 = nb * 128;

  f32x4 acc[4][4];
  #pragma unroll
  for (int m = 0; m < 4; ++m)
    #pragma unroll
    for (int n = 0; n < 4; ++n)
      acc[m][n] = (f32x4){0.f, 0.f, 0.f, 0.f};

  for (int k0 = 0; k0 < 256; k0 += 32) {
    if (w < 2) {
      #pragma unroll
      for (int j = 0; j < 4; ++j) {
        int i = w * 4 + j;
        int kq = i >> 1, half = i & 1;
        const u16* g = A + ((size_t)(r0 + half * 64 + l)) * 256 + k0 + kq * 8;
        __builtin_amdgcn_global_load_lds((const as1_u32*)g, (as3_u32*)(smem + i * 1024), 16, 0, 0);
      }
    } else {
      #pragma unroll
      for (int j = 0; j < 4; ++j) {
        int i = (w - 2) * 4 + j;
        int kq = i >> 1, half = i & 1;
        const u16* g = Bw + ((size_t)(n0 + half * 64 + l)) * 256 + k0 + kq * 8;
        __builtin_amdgcn_global_load_lds((const as1_u32*)g, (as3_u32*)(smem + 8192 + i * 1024), 16, 0, 0);
      }
    }
    __syncthreads();

    const int kq = l >> 4, lr = l & 15;
    bf16x8 af[4], bfr[4];
    #pragma unroll
    for (int m = 0; m < 4; ++m)
      af[m] = *(const bf16x8*)(smem + (kq * 128 + wm * 64 + m * 16 + lr) * 16);
    #pragma unroll
    for (int n = 0; n < 4; ++n)
      bfr[n] = *(const bf16x8*)(smem + 8192 + (kq * 128 + wn * 64 + n * 16 + lr) * 16);
    #pragma unroll
    for (int m = 0; m < 4; ++m)
      #pragma unroll
      for (int n = 0; n < 4; ++n)
        acc[m][n] = __builtin_amdgcn_mfma_f32_16x16x32_bf16(af[m], bfr[n], acc[m][n], 0, 0, 0);
    __syncthreads();
  }

  const int lr = l & 15, lq = l >> 4;
  #pragma unroll
  for (int n = 0; n < 4; ++n) {
    int col = n0 + wn * 64 + n * 16 + lr;
    float bv = bias[col];
    #pragma unroll
    for (int m = 0; m < 4; ++m) {
      int row = r0 + wm * 64 + m * 16 + lq * 4;
      #pragma unroll
      for (int r = 0; r < 4; ++r)
        out[(size_t)(row + r) * 256 + col] = acc[m][n][r] + bv;
    }
  }
}

// ---------------------------------------------------------------------------
extern "C" void kernel_launch(void* const* d_in, const int* in_sizes, int n_in,
                              void* d_out, int out_size, void* d_ws, size_t ws_size,
                              hipStream_t stream) {
  const float* query  = (const float*)d_in[0];
  const float* key    = (const float*)d_in[1];
  const float* w_off  = (const float*)d_in[2];
  const float* b_off  = (const float*)d_in[3];
  const float* w_proj = (const float*)d_in[4];
  const float* b_proj = (const float*)d_in[5];
  float* out = (float*)d_out;

  char* ws = (char*)d_ws;
  uint2*  wpk      = (uint2*)ws;                                //  8 MB
  u32*    idx4     = (u32*)(ws + (size_t)8  * 1024 * 1024);     //  4 MB
  u32*    key_t2   = (u32*)(ws + (size_t)16 * 1024 * 1024);     // 16 MB
  u32*    feat2    = (u32*)(ws + (size_t)32 * 1024 * 1024);     // 16 MB
  uint2*  wproj_bf = (uint2*)(ws + (size_t)48 * 1024 * 1024);   // 128 KB

  hipLaunchKernelGGL(k_trans_conv,   dim3(4160),  dim3(256), 0, stream,
                     key, w_proj, key_t2, wproj_bf);
  hipLaunchKernelGGL(k_offsets_mfma, dim3(512),   dim3(256), 0, stream,
                     query, w_off, b_off, wpk, idx4);
  hipLaunchKernelGGL(k_sample,       dim3(16384), dim3(256), 0, stream,
                     wpk, idx4, key_t2, feat2);
  hipLaunchKernelGGL(k_proj_mfma,    dim3(512),   dim3(256), 0, stream,
                     (const u16*)feat2, (const u16*)wproj_bf, b_proj, out);
}